// Round 12
// baseline (10647.689 us; speedup 1.0000x reference)
//
#include <hip/hip_runtime.h>

#define TT 1000
#define HH 512
#define G4 2048
#define NG 32         // groups
#define SLOTS 8       // blocks per group
#define SPG 4         // seqs per group
#define HCBLK 64      // h-cols per block

typedef __attribute__((ext_vector_type(8))) short bf16x8;
typedef __attribute__((ext_vector_type(4))) float f32x4;

__device__ __forceinline__ float sigm(float v) { return 1.0f / (1.0f + __expf(-v)); }
__device__ __forceinline__ float tanh_fast(float v) { return 2.0f / (1.0f + __expf(-2.0f * v)) - 1.0f; }

__device__ __forceinline__ unsigned short bf16rne(float f) {
    unsigned u = __float_as_uint(f);
    return (unsigned short)((u + 0x7fffu + ((u >> 16) & 1u)) >> 16);
}

// 256 blocks x 512 thr (8 waves). group g = bid&31 owns seqs [g*4,+4);
// slot = bid>>5 owns h-cols [slot*64,+64); wave wv owns 8 cols. W_hh in VGPRs.
// BARRIER-FREE: h travels as self-tagged u64 (4 bf16, bit14 free since
// |h|<1 -> carries a mod-16 step tag). Producers fire-and-forget one agent
// u64 store; each WAVE independently polls its 4KB group slab (8 coalesced
// u64/lane), strips tags, writes its PRIVATE LDS region (no __syncthreads
// in the loop at all). Chain: compute -> store -> visibility -> poll-hit.
// Safety: wave enters step s+2 only after all waves stored tag s+2, so no
// reader of tag s+1 remains when tag s+3 overwrites its phase slot.
__global__ __launch_bounds__(512, 1)
void lstm_wf(const float* __restrict__ x,     // [B][T][2]
             const float* __restrict__ wih,   // [2][4H]
             const float* __restrict__ whh,   // [H][4H]
             const float* __restrict__ bias,  // [4H]
             float* __restrict__ out,         // h [B][T][H] then c [B][T][H]
             float* ws)
{
    // per-wave private A-slab: [wave][row 0..3][132 u64]; stride 132 staggers
    // rows by 2 16B-slots (mod 8) -> 2-way (free) MFMA read conflicts.
    __shared__ unsigned long long lds64[8][4][132];

    const int bid  = blockIdx.x;
    const int g    = bid & (NG - 1);
    const int slot = bid >> 5;
    const int tid  = threadIdx.x;
    const int wv   = tid >> 6;             // 0..7
    const int lane = tid & 63;
    const int col  = lane & 15;
    const int kb   = lane >> 4;            // 0..3 (k-subchunk / A row-group)
    const int q    = col & 3;              // gate id 0=f,1=i,2=o,3=g
    const int q1   = q & 1, q2 = q >> 1;
    const int cc   = col >> 2;             // within-tile h-col 0..3
    const int hc0  = slot * HCBLK + wv * 8 + cc;   // tile0 h-col
    const int hc1  = hc0 + 4;                      // tile1 h-col

    unsigned long long* slab = (unsigned long long*)ws;   // u64[2][128][128]
    const unsigned long long TAGM = 0x4000400040004000ULL;

    // zero own wave region (t=0 state: h(0)=0)
    for (int i = lane; i < 4 * 132; i += 64)
        ((unsigned long long*)lds64[wv])[i] = 0ULL;

    // ---- one-time: W_hh fragments into registers (2 tiles x 64 VGPR) ----
    const int gc0 = q * 512 + hc0;
    const int gc1 = q * 512 + hc1;
    bf16x8 breg0[16], breg1[16];
    #pragma unroll
    for (int kt = 0; kt < 16; ++kt) {
        bf16x8 f0, f1;
        #pragma unroll
        for (int j = 0; j < 8; ++j) {
            int k = kt * 32 + kb * 8 + j;
            f0[j] = (short)bf16rne(whh[(size_t)k * G4 + gc0]);
            f1[j] = (short)bf16rne(whh[(size_t)k * G4 + gc1]);
        }
        breg0[kt] = f0;
        breg1[kt] = f1;
    }

    float wA0[4], wB0[4], bb0[4], wA1[4], wB1[4], bb1[4];
    #pragma unroll
    for (int j = 0; j < 4; ++j) {
        int a0 = j * 512 + hc0, a1 = j * 512 + hc1;
        wA0[j] = wih[a0]; wB0[j] = wih[G4 + a0]; bb0[j] = bias[a0];
        wA1[j] = wih[a1]; wB1[j] = wih[G4 + a1]; bb1[j] = bias[a1];
    }

    float cst0 = 0.0f, cst1 = 0.0f;
    const size_t OSZ = (size_t)128 * TT * HH;
    const int bSel = g * SPG + q;          // batch index (valid for kb==0 lanes)
    const float* xp = x + (size_t)bSel * TT * 2;
    float2 xv = *(const float2*)(xp);      // x(0) prefetched
    const bool storer = (kb == 0) && (cc == 0);

    for (int t = 0; t < TT; ++t) {
        // ---- gates = h @ W_hh (K=512; A rows 4..15 are zero) ----
        f32x4 acc0 = {0.f, 0.f, 0.f, 0.f};
        f32x4 acc1 = {0.f, 0.f, 0.f, 0.f};
        #pragma unroll
        for (int kt = 0; kt < 16; ++kt) {
            bf16x8 a = {0, 0, 0, 0, 0, 0, 0, 0};
            if (col < 4)
                a = *(const bf16x8*)&lds64[wv][col][(kt * 8 + kb * 2) ^ (2 * col)];
            acc0 = __builtin_amdgcn_mfma_f32_16x16x32_bf16(a, breg0[kt], acc0, 0, 0, 0);
            acc1 = __builtin_amdgcn_mfma_f32_16x16x32_bf16(a, breg1[kt], acc1, 0, 0, 0);
        }

        // ---- tile 0: quad butterfly + gate math ----
        float h1a, c1a;
        {
            float v0 = acc0[0], v1 = acc0[1], v2 = acc0[2], v3 = acc0[3];
            float vq = q2 ? (q1 ? v3 : v2) : (q1 ? v1 : v0);
            float s1 = q2 ? (q1 ? v2 : v3) : (q1 ? v0 : v1);
            float s2 = q2 ? (q1 ? v1 : v0) : (q1 ? v3 : v2);
            float s3 = q2 ? (q1 ? v0 : v1) : (q1 ? v2 : v3);
            float g1 = __shfl_xor(s1, 1);
            float g2 = __shfl_xor(s2, 2);
            float g3 = __shfl_xor(s3, 3);
            float fv = q2 ? (q1 ? g3 : g2) : (q1 ? g1 : vq);
            float iv = q2 ? (q1 ? g2 : g3) : (q1 ? vq : g1);
            float ov = q2 ? (q1 ? g1 : vq) : (q1 ? g3 : g2);
            float gv = q2 ? (q1 ? vq : g1) : (q1 ? g2 : g3);
            fv += xv.x * wA0[0] + xv.y * wB0[0] + bb0[0];
            iv += xv.x * wA0[1] + xv.y * wB0[1] + bb0[1];
            ov += xv.x * wA0[2] + xv.y * wB0[2] + bb0[2];
            gv += xv.x * wA0[3] + xv.y * wB0[3] + bb0[3];
            c1a = sigm(fv) * cst0 + sigm(iv) * tanh_fast(gv);
            h1a = sigm(ov) * tanh_fast(c1a);
            cst0 = c1a;
        }
        // ---- tile 1 ----
        float h1b, c1b;
        {
            float v0 = acc1[0], v1 = acc1[1], v2 = acc1[2], v3 = acc1[3];
            float vq = q2 ? (q1 ? v3 : v2) : (q1 ? v1 : v0);
            float s1 = q2 ? (q1 ? v2 : v3) : (q1 ? v0 : v1);
            float s2 = q2 ? (q1 ? v1 : v0) : (q1 ? v3 : v2);
            float s3 = q2 ? (q1 ? v0 : v1) : (q1 ? v2 : v3);
            float g1 = __shfl_xor(s1, 1);
            float g2 = __shfl_xor(s2, 2);
            float g3 = __shfl_xor(s3, 3);
            float fv = q2 ? (q1 ? g3 : g2) : (q1 ? g1 : vq);
            float iv = q2 ? (q1 ? g2 : g3) : (q1 ? vq : g1);
            float ov = q2 ? (q1 ? g1 : vq) : (q1 ? g3 : g2);
            float gv = q2 ? (q1 ? vq : g1) : (q1 ? g2 : g3);
            fv += xv.x * wA1[0] + xv.y * wB1[0] + bb1[0];
            iv += xv.x * wA1[1] + xv.y * wB1[1] + bb1[1];
            ov += xv.x * wA1[2] + xv.y * wB1[2] + bb1[2];
            gv += xv.x * wA1[3] + xv.y * wB1[3] + bb1[3];
            c1b = sigm(fv) * cst1 + sigm(iv) * tanh_fast(gv);
            h1b = sigm(ov) * tanh_fast(c1b);
            cst1 = c1b;
        }

        // ---- pack h,c across cc via shuffles ----
        float ha1 = __shfl_xor(h1a, 4), ha2 = __shfl_xor(h1a, 8), ha3 = __shfl_xor(ha1, 8);
        float hb1 = __shfl_xor(h1b, 4), hb2 = __shfl_xor(h1b, 8), hb3 = __shfl_xor(hb1, 8);
        float ca1 = __shfl_xor(c1a, 4), ca2 = __shfl_xor(c1a, 8), ca3 = __shfl_xor(ca1, 8);
        float cb1 = __shfl_xor(c1b, 4), cb2 = __shfl_xor(c1b, 8), cb3 = __shfl_xor(cb1, 8);

        const unsigned tag4 = (unsigned)(t + 1) & 15u;
        const int phase = (t + 1) & 1;
        const unsigned long long tpat =
              ((unsigned long long)(tag4 & 1u)        << 14)
            | ((unsigned long long)((tag4 >> 1) & 1u) << 30)
            | ((unsigned long long)((tag4 >> 2) & 1u) << 46)
            | ((unsigned long long)((tag4 >> 3) & 1u) << 62);

        // ---- producer: one tagged u64 pair, fire-and-forget ----
        if (t + 1 < TT && storer) {
            unsigned long long w0 =
                  (unsigned long long)bf16rne(h1a)
                | ((unsigned long long)bf16rne(ha1) << 16)
                | ((unsigned long long)bf16rne(ha2) << 32)
                | ((unsigned long long)bf16rne(ha3) << 48) | tpat;
            unsigned long long w1 =
                  (unsigned long long)bf16rne(h1b)
                | ((unsigned long long)bf16rne(hb1) << 16)
                | ((unsigned long long)bf16rne(hb2) << 32)
                | ((unsigned long long)bf16rne(hb3) << 48) | tpat;
            unsigned long long* dst = slab
                + ((size_t)(phase * 128 + bSel)) * 128 + slot * 16 + wv * 2;
            __hip_atomic_store(dst,     w0, __ATOMIC_RELAXED, __HIP_MEMORY_SCOPE_AGENT);
            __hip_atomic_store(dst + 1, w1, __ATOMIC_RELAXED, __HIP_MEMORY_SCOPE_AGENT);
        }

        // ---- out flush (acks overlap the poll's visibility wait) ----
        if (storer) {
            size_t oidx = ((size_t)bSel * TT + t) * HH + slot * HCBLK + wv * 8;
            float4 hq0 = {h1a, ha1, ha2, ha3};
            float4 cq0 = {c1a, ca1, ca2, ca3};
            float4 hq1 = {h1b, hb1, hb2, hb3};
            float4 cq1 = {c1b, cb1, cb2, cb3};
            *(float4*)(out + oidx) = hq0;
            *(float4*)(out + oidx + 4) = hq1;
            *(float4*)(out + OSZ + oidx) = cq0;
            *(float4*)(out + OSZ + oidx + 4) = cq1;
        }

        if (t + 1 < TT) {
            xv = *(const float2*)(xp + 2 * (t + 1));   // prefetch x(t+1)

            // ---- per-wave poll: 8 coalesced u64/lane, in-band tag check ----
            const unsigned long long* src = slab
                + ((size_t)(phase * 128 + g * SPG)) * 128;
            unsigned long long vals[8];
            #pragma unroll
            for (int j = 0; j < 8; ++j)
                vals[j] = __hip_atomic_load(src + j * 64 + lane,
                              __ATOMIC_RELAXED, __HIP_MEMORY_SCOPE_AGENT);
            unsigned pend = 0u;
            #pragma unroll
            for (int j = 0; j < 8; ++j)
                if ((vals[j] & TAGM) != tpat) pend |= (1u << j);

            long gd = 0;
            while (pend) {
                __builtin_amdgcn_s_sleep(1);
                #pragma unroll
                for (int j = 0; j < 8; ++j) if (pend & (1u << j)) {
                    unsigned long long v = __hip_atomic_load(src + j * 64 + lane,
                            __ATOMIC_RELAXED, __HIP_MEMORY_SCOPE_AGENT);
                    if ((v & TAGM) == tpat) { vals[j] = v; pend &= ~(1u << j); }
                }
                if (++gd > 20000000L) break;   // anti-hang escape
            }

            // ---- consume into own wave's LDS region (no barrier needed) ----
            // u64 index j*64+lane -> row = j>>1, k0u64 = (j&1)*64+lane;
            // phys = k0u64 ^ (2*row)  (write conflict-free; read 2-way)
            #pragma unroll
            for (int j = 0; j < 8; ++j) {
                const int row = j >> 1;
                lds64[wv][row][(((j & 1) * 64 + lane) ^ (2 * row))] = vals[j] & ~TAGM;
            }
        }
    }
}

extern "C" void kernel_launch(void* const* d_in, const int* in_sizes, int n_in,
                              void* d_out, int out_size, void* d_ws, size_t ws_size,
                              hipStream_t stream) {
    const float* x    = (const float*)d_in[0];
    const float* wih  = (const float*)d_in[1];
    const float* whh  = (const float*)d_in[2];
    const float* bias = (const float*)d_in[3];
    float* out = (float*)d_out;
    float* ws  = (float*)d_ws;

    // zero the tagged slab every launch (tag bits invalid; graph replay safe)
    hipMemsetAsync(d_ws, 0, 2 * 128 * 128 * sizeof(unsigned long long), stream);

    dim3 grid(NG * SLOTS), block(512);
    hipLaunchKernelGGL(lstm_wf, grid, block, 0, stream, x, wih, whh, bias, out, ws);
}

// Round 13
// 5196.502 us; speedup vs baseline: 2.0490x; 2.0490x over previous
//
#include <hip/hip_runtime.h>

#define TT 1000
#define HH 512
#define G4 2048
#define NG 32         // groups
#define SLOTS 8       // blocks per group
#define SPG 4         // seqs per group
#define HCBLK 64      // h-cols per block

typedef __attribute__((ext_vector_type(8))) short bf16x8;
typedef __attribute__((ext_vector_type(4))) float f32x4;

__device__ __forceinline__ float sigm(float v) { return 1.0f / (1.0f + __expf(-v)); }
__device__ __forceinline__ float tanh_fast(float v) { return 2.0f / (1.0f + __expf(-2.0f * v)) - 1.0f; }

__device__ __forceinline__ unsigned short bf16rne(float f) {
    unsigned u = __float_as_uint(f);
    return (unsigned short)((u + 0x7fffu + ((u >> 16) & 1u)) >> 16);
}

// 256 blocks x 512 thr (8 waves, 1/CU). group g = bid&31 owns seqs [g*4,+4);
// slot = bid>>5 owns h-cols [slot*64,+64). W_hh in VGPRs (2 tiles/wave).
// Exchange: in-band tagged u64 (4 bf16; |h|<=1 -> bit14 free -> mod-16 step
// tag), fire-and-forget agent store; consume = EXACTLY ONE u64 per thread
// (512 thr <-> 512 slab words), per-lane retry of own word only. LDS A-slab
// double-buffered by step parity -> ONE __syncthreads per step, no vmcnt, no
// flags. Safety: skew <= 2 steps, tag diff 2 mod 16 != 0; u64 stores atomic.
__global__ __launch_bounds__(512, 1)
void lstm_tg8(const float* __restrict__ x,     // [B][T][2]
              const float* __restrict__ wih,   // [2][4H]
              const float* __restrict__ whh,   // [H][4H]
              const float* __restrict__ bias,  // [4H]
              float* __restrict__ out,         // h [B][T][H] then c [B][T][H]
              float* ws)
{
    // A-slab: [buf][row 0..3][132 u64]; stride 132 staggers banks (R12: zero
    // conflicts with the ^(2*row) swizzle). Rows 4..15 of MFMA A are zero via
    // exec-masked reads (col<4 only).
    __shared__ unsigned long long ldsA[2][4][132];

    const int bid  = blockIdx.x;
    const int g    = bid & (NG - 1);
    const int slot = bid >> 5;
    const int tid  = threadIdx.x;
    const int wv   = tid >> 6;             // 0..7
    const int lane = tid & 63;
    const int col  = lane & 15;
    const int kb   = lane >> 4;            // 0..3 (k-subchunk)
    const int q    = col & 3;              // gate id 0=f,1=i,2=o,3=g
    const int q1   = q & 1, q2 = q >> 1;
    const int cc   = col >> 2;             // within-tile h-col 0..3
    const int hc0  = slot * HCBLK + wv * 8 + cc;
    const int hc1  = hc0 + 4;

    unsigned long long* slab = (unsigned long long*)ws;   // u64[2][128][128]
    const unsigned long long TAGM = 0x4000400040004000ULL;

    // zero both LDS buffers (buf0 = h(0) = 0)
    for (int i = tid; i < 2 * 4 * 132; i += 512)
        ((unsigned long long*)ldsA)[i] = 0ULL;

    // ---- one-time: W_hh fragments into registers (2 tiles x 64 VGPR) ----
    const int gc0 = q * 512 + hc0;
    const int gc1 = q * 512 + hc1;
    bf16x8 breg0[16], breg1[16];
    #pragma unroll
    for (int kt = 0; kt < 16; ++kt) {
        bf16x8 f0, f1;
        #pragma unroll
        for (int j = 0; j < 8; ++j) {
            int k = kt * 32 + kb * 8 + j;
            f0[j] = (short)bf16rne(whh[(size_t)k * G4 + gc0]);
            f1[j] = (short)bf16rne(whh[(size_t)k * G4 + gc1]);
        }
        breg0[kt] = f0;
        breg1[kt] = f1;
    }

    float wA0[4], wB0[4], bb0[4], wA1[4], wB1[4], bb1[4];
    #pragma unroll
    for (int j = 0; j < 4; ++j) {
        int a0 = j * 512 + hc0, a1 = j * 512 + hc1;
        wA0[j] = wih[a0]; wB0[j] = wih[G4 + a0]; bb0[j] = bias[a0];
        wA1[j] = wih[a1]; wB1[j] = wih[G4 + a1]; bb1[j] = bias[a1];
    }

    float cst0 = 0.0f, cst1 = 0.0f;
    const size_t OSZ = (size_t)128 * TT * HH;
    const int bSel = g * SPG + q;          // batch index for this lane's row
    const float* xp = x + (size_t)bSel * TT * 2;
    float2 xv = *(const float2*)(xp);      // x(0) prefetched
    const bool storer = (kb == 0) && (cc == 0);

    // this thread's consume word: row crow, u64 ck within the row
    const int crow = tid >> 7;             // 0..3
    const int ck   = tid & 127;            // 0..127

    __syncthreads();

    for (int t = 0; t < TT; ++t) {
        const int rb = t & 1;              // read buffer (h(t))

        // ---- gates = h @ W_hh (K=512; A rows 4..15 zero via exec mask) ----
        f32x4 acc0 = {0.f, 0.f, 0.f, 0.f};
        f32x4 acc1 = {0.f, 0.f, 0.f, 0.f};
        #pragma unroll
        for (int kt = 0; kt < 16; ++kt) {
            bf16x8 a = {0, 0, 0, 0, 0, 0, 0, 0};
            if (col < 4)
                a = *(const bf16x8*)&ldsA[rb][col][(kt * 8 + kb * 2) ^ (2 * col)];
            acc0 = __builtin_amdgcn_mfma_f32_16x16x32_bf16(a, breg0[kt], acc0, 0, 0, 0);
            acc1 = __builtin_amdgcn_mfma_f32_16x16x32_bf16(a, breg1[kt], acc1, 0, 0, 0);
        }

        // ---- tile 0: quad butterfly + gate math ----
        float h1a, c1a;
        {
            float v0 = acc0[0], v1 = acc0[1], v2 = acc0[2], v3 = acc0[3];
            float vq = q2 ? (q1 ? v3 : v2) : (q1 ? v1 : v0);
            float s1 = q2 ? (q1 ? v2 : v3) : (q1 ? v0 : v1);
            float s2 = q2 ? (q1 ? v1 : v0) : (q1 ? v3 : v2);
            float s3 = q2 ? (q1 ? v0 : v1) : (q1 ? v2 : v3);
            float g1 = __shfl_xor(s1, 1);
            float g2 = __shfl_xor(s2, 2);
            float g3 = __shfl_xor(s3, 3);
            float fv = q2 ? (q1 ? g3 : g2) : (q1 ? g1 : vq);
            float iv = q2 ? (q1 ? g2 : g3) : (q1 ? vq : g1);
            float ov = q2 ? (q1 ? g1 : vq) : (q1 ? g3 : g2);
            float gv = q2 ? (q1 ? vq : g1) : (q1 ? g2 : g3);
            fv += xv.x * wA0[0] + xv.y * wB0[0] + bb0[0];
            iv += xv.x * wA0[1] + xv.y * wB0[1] + bb0[1];
            ov += xv.x * wA0[2] + xv.y * wB0[2] + bb0[2];
            gv += xv.x * wA0[3] + xv.y * wB0[3] + bb0[3];
            c1a = sigm(fv) * cst0 + sigm(iv) * tanh_fast(gv);
            h1a = sigm(ov) * tanh_fast(c1a);
            cst0 = c1a;
        }
        // ---- tile 1 ----
        float h1b, c1b;
        {
            float v0 = acc1[0], v1 = acc1[1], v2 = acc1[2], v3 = acc1[3];
            float vq = q2 ? (q1 ? v3 : v2) : (q1 ? v1 : v0);
            float s1 = q2 ? (q1 ? v2 : v3) : (q1 ? v0 : v1);
            float s2 = q2 ? (q1 ? v1 : v0) : (q1 ? v3 : v2);
            float s3 = q2 ? (q1 ? v0 : v1) : (q1 ? v2 : v3);
            float g1 = __shfl_xor(s1, 1);
            float g2 = __shfl_xor(s2, 2);
            float g3 = __shfl_xor(s3, 3);
            float fv = q2 ? (q1 ? g3 : g2) : (q1 ? g1 : vq);
            float iv = q2 ? (q1 ? g2 : g3) : (q1 ? vq : g1);
            float ov = q2 ? (q1 ? g1 : vq) : (q1 ? g3 : g2);
            float gv = q2 ? (q1 ? vq : g1) : (q1 ? g2 : g3);
            fv += xv.x * wA1[0] + xv.y * wB1[0] + bb1[0];
            iv += xv.x * wA1[1] + xv.y * wB1[1] + bb1[1];
            ov += xv.x * wA1[2] + xv.y * wB1[2] + bb1[2];
            gv += xv.x * wA1[3] + xv.y * wB1[3] + bb1[3];
            c1b = sigm(fv) * cst1 + sigm(iv) * tanh_fast(gv);
            h1b = sigm(ov) * tanh_fast(c1b);
            cst1 = c1b;
        }

        // ---- pack h,c across cc via shuffles ----
        float ha1 = __shfl_xor(h1a, 4), ha2 = __shfl_xor(h1a, 8), ha3 = __shfl_xor(ha1, 8);
        float hb1 = __shfl_xor(h1b, 4), hb2 = __shfl_xor(h1b, 8), hb3 = __shfl_xor(hb1, 8);
        float ca1 = __shfl_xor(c1a, 4), ca2 = __shfl_xor(c1a, 8), ca3 = __shfl_xor(ca1, 8);
        float cb1 = __shfl_xor(c1b, 4), cb2 = __shfl_xor(c1b, 8), cb3 = __shfl_xor(cb1, 8);

        const unsigned tag4 = (unsigned)(t + 1) & 15u;
        const int phase = (t + 1) & 1;
        const unsigned long long tpat =
              ((unsigned long long)(tag4 & 1u)        << 14)
            | ((unsigned long long)((tag4 >> 1) & 1u) << 30)
            | ((unsigned long long)((tag4 >> 2) & 1u) << 46)
            | ((unsigned long long)((tag4 >> 3) & 1u) << 62);

        // ---- producer: 2 tagged u64, fire-and-forget (no ack, no flag) ----
        if (t + 1 < TT && storer) {
            unsigned long long w0 =
                  (unsigned long long)bf16rne(h1a)
                | ((unsigned long long)bf16rne(ha1) << 16)
                | ((unsigned long long)bf16rne(ha2) << 32)
                | ((unsigned long long)bf16rne(ha3) << 48) | tpat;
            unsigned long long w1 =
                  (unsigned long long)bf16rne(h1b)
                | ((unsigned long long)bf16rne(hb1) << 16)
                | ((unsigned long long)bf16rne(hb2) << 32)
                | ((unsigned long long)bf16rne(hb3) << 48) | tpat;
            unsigned long long* dst = slab
                + ((size_t)(phase * 128 + bSel)) * 128 + slot * 16 + wv * 2;
            __hip_atomic_store(dst,     w0, __ATOMIC_RELAXED, __HIP_MEMORY_SCOPE_AGENT);
            __hip_atomic_store(dst + 1, w1, __ATOMIC_RELAXED, __HIP_MEMORY_SCOPE_AGENT);
        }

        // ---- out flush (fire-and-forget; acks never block the chain) ----
        if (storer) {
            size_t oidx = ((size_t)bSel * TT + t) * HH + slot * HCBLK + wv * 8;
            float4 hq0 = {h1a, ha1, ha2, ha3};
            float4 cq0 = {c1a, ca1, ca2, ca3};
            float4 hq1 = {h1b, hb1, hb2, hb3};
            float4 cq1 = {c1b, cb1, cb2, cb3};
            *(float4*)(out + oidx) = hq0;
            *(float4*)(out + oidx + 4) = hq1;
            *(float4*)(out + OSZ + oidx) = cq0;
            *(float4*)(out + OSZ + oidx + 4) = cq1;
        }

        if (t + 1 < TT) {
            xv = *(const float2*)(xp + 2 * (t + 1));   // prefetch x(t+1)

            // ---- consume: ONE u64 per thread, retry own word only ----
            const unsigned long long* myp = slab
                + ((size_t)(phase * 128 + g * SPG + crow)) * 128 + ck;
            unsigned long long d = __hip_atomic_load(myp, __ATOMIC_RELAXED,
                                                     __HIP_MEMORY_SCOPE_AGENT);
            long gd = 0;
            while ((d & TAGM) != tpat) {
                __builtin_amdgcn_s_sleep(1);
                d = __hip_atomic_load(myp, __ATOMIC_RELAXED,
                                      __HIP_MEMORY_SCOPE_AGENT);
                if (++gd > 3000000L) break;   // anti-hang escape
            }
            ldsA[phase][crow][ck ^ (2 * crow)] = d & ~TAGM;

            __syncthreads();   // the ONLY barrier per step
        }
    }
}

extern "C" void kernel_launch(void* const* d_in, const int* in_sizes, int n_in,
                              void* d_out, int out_size, void* d_ws, size_t ws_size,
                              hipStream_t stream) {
    const float* x    = (const float*)d_in[0];
    const float* wih  = (const float*)d_in[1];
    const float* whh  = (const float*)d_in[2];
    const float* bias = (const float*)d_in[3];
    float* out = (float*)d_out;
    float* ws  = (float*)d_ws;

    // zero the tagged slab every launch (stale tags invalid; graph replay safe)
    hipMemsetAsync(d_ws, 0, 2 * 128 * 128 * sizeof(unsigned long long), stream);

    dim3 grid(NG * SLOTS), block(512);
    hipLaunchKernelGGL(lstm_tg8, grid, block, 0, stream, x, wih, whh, bias, out, ws);
}

// Round 14
// 3388.776 us; speedup vs baseline: 3.1420x; 1.5334x over previous
//
#include <hip/hip_runtime.h>

#define TT 1000
#define HH 512
#define G4 2048
#define NG 32         // groups
#define SLOTS 8       // blocks per group
#define SPG 4         // seqs per group
#define HCBLK 64      // h-cols per block

typedef __attribute__((ext_vector_type(8))) short bf16x8;
typedef __attribute__((ext_vector_type(4))) float f32x4;

__device__ __forceinline__ float sigm(float v) { return 1.0f / (1.0f + __expf(-v)); }
__device__ __forceinline__ float tanh_fast(float v) { return 2.0f / (1.0f + __expf(-2.0f * v)) - 1.0f; }

__device__ __forceinline__ unsigned short bf16rne(float f) {
    unsigned u = __float_as_uint(f);
    return (unsigned short)((u + 0x7fffu + ((u >> 16) & 1u)) >> 16);
}

// 256 blocks x 512 thr (8 waves, 1/CU). group g = bid&31 owns seqs [g*4,+4);
// slot = bid>>5 owns h-cols [slot*64,+64). W_hh in VGPRs (2 tiles/wave).
// Protocol = R11 flag-then-bulk, minus every vmcnt drain:
//  - producer slab stores carry IN-BAND tags (|h|<=1 -> bf16 bit14 free) and
//    are fire-and-forget; NO ack. Tags are the correctness guarantee.
//  - flag (stored after a RAW issue-barrier) is only a HINT that data arrived;
//    consumers poll 8 flag lines, then bulk-read 1 u64/thread, validate tags,
//    retry only stale words (rare).
//  - barriers are raw s_barrier + lgkmcnt(0) (no vmcnt): LDS double-buffer
//    makes them sufficient (buf reads/writes separated by >=2 barriers).
//  - out-stores issue after the refill so their HBM acks block nothing.
__global__ __launch_bounds__(512, 1)
void lstm_fb(const float* __restrict__ x,     // [B][T][2]
             const float* __restrict__ wih,   // [2][4H]
             const float* __restrict__ whh,   // [H][4H]
             const float* __restrict__ bias,  // [4H]
             float* __restrict__ out,         // h [B][T][H] then c [B][T][H]
             float* ws)
{
    // A-slab: [buf][row 0..3][132 u64]; ^(2*row) swizzle = zero conflicts (R12/R13)
    __shared__ unsigned long long ldsA[2][4][132];

    const int bid  = blockIdx.x;
    const int g    = bid & (NG - 1);
    const int slot = bid >> 5;
    const int tid  = threadIdx.x;
    const int wv   = tid >> 6;             // 0..7
    const int lane = tid & 63;
    const int col  = lane & 15;
    const int kb   = lane >> 4;            // 0..3 (k-subchunk)
    const int q    = col & 3;              // gate id 0=f,1=i,2=o,3=g
    const int q1   = q & 1, q2 = q >> 1;
    const int cc   = col >> 2;             // within-tile h-col 0..3
    const int hc0  = slot * HCBLK + wv * 8 + cc;
    const int hc1  = hc0 + 4;

    unsigned long long* slab = (unsigned long long*)ws;          // u64[2][128][128]
    unsigned* flags = (unsigned*)((char*)ws + 256 * 1024);       // [32][8] x 64B
    const unsigned long long TAGM = 0x4000400040004000ULL;

    // zero both LDS buffers (buf0 = h(0) = 0)
    for (int i = tid; i < 2 * 4 * 132; i += 512)
        ((unsigned long long*)ldsA)[i] = 0ULL;

    // ---- one-time: W_hh fragments into registers (2 tiles x 64 VGPR) ----
    const int gc0 = q * 512 + hc0;
    const int gc1 = q * 512 + hc1;
    bf16x8 breg0[16], breg1[16];
    #pragma unroll
    for (int kt = 0; kt < 16; ++kt) {
        bf16x8 f0, f1;
        #pragma unroll
        for (int j = 0; j < 8; ++j) {
            int k = kt * 32 + kb * 8 + j;
            f0[j] = (short)bf16rne(whh[(size_t)k * G4 + gc0]);
            f1[j] = (short)bf16rne(whh[(size_t)k * G4 + gc1]);
        }
        breg0[kt] = f0;
        breg1[kt] = f1;
    }

    float wA0[4], wB0[4], bb0[4], wA1[4], wB1[4], bb1[4];
    #pragma unroll
    for (int j = 0; j < 4; ++j) {
        int a0 = j * 512 + hc0, a1 = j * 512 + hc1;
        wA0[j] = wih[a0]; wB0[j] = wih[G4 + a0]; bb0[j] = bias[a0];
        wA1[j] = wih[a1]; wB1[j] = wih[G4 + a1]; bb1[j] = bias[a1];
    }

    float cst0 = 0.0f, cst1 = 0.0f;
    const size_t OSZ = (size_t)128 * TT * HH;
    const int bSel = g * SPG + q;          // batch index for this lane's row
    const float* xp = x + (size_t)bSel * TT * 2;
    float2 xv = *(const float2*)(xp);      // x(0) prefetched
    const bool storer = (kb == 0) && (cc == 0);

    // this thread's refill word: row crow, u64 ck within the row
    const int crow = tid >> 7;             // 0..3
    const int ck   = tid & 127;            // 0..127

    __syncthreads();

    for (int t = 0; t < TT; ++t) {
        const int rb = t & 1;              // read buffer (h(t))

        // ---- gates = h @ W_hh (K=512; A rows 4..15 zero via exec mask) ----
        f32x4 acc0 = {0.f, 0.f, 0.f, 0.f};
        f32x4 acc1 = {0.f, 0.f, 0.f, 0.f};
        #pragma unroll
        for (int kt = 0; kt < 16; ++kt) {
            bf16x8 a = {0, 0, 0, 0, 0, 0, 0, 0};
            if (col < 4)
                a = *(const bf16x8*)&ldsA[rb][col][(kt * 8 + kb * 2) ^ (2 * col)];
            acc0 = __builtin_amdgcn_mfma_f32_16x16x32_bf16(a, breg0[kt], acc0, 0, 0, 0);
            acc1 = __builtin_amdgcn_mfma_f32_16x16x32_bf16(a, breg1[kt], acc1, 0, 0, 0);
        }

        // ---- tile 0: quad butterfly + gate math ----
        float h1a, c1a;
        {
            float v0 = acc0[0], v1 = acc0[1], v2 = acc0[2], v3 = acc0[3];
            float vq = q2 ? (q1 ? v3 : v2) : (q1 ? v1 : v0);
            float s1 = q2 ? (q1 ? v2 : v3) : (q1 ? v0 : v1);
            float s2 = q2 ? (q1 ? v1 : v0) : (q1 ? v3 : v2);
            float s3 = q2 ? (q1 ? v0 : v1) : (q1 ? v2 : v3);
            float g1 = __shfl_xor(s1, 1);
            float g2 = __shfl_xor(s2, 2);
            float g3 = __shfl_xor(s3, 3);
            float fv = q2 ? (q1 ? g3 : g2) : (q1 ? g1 : vq);
            float iv = q2 ? (q1 ? g2 : g3) : (q1 ? vq : g1);
            float ov = q2 ? (q1 ? g1 : vq) : (q1 ? g3 : g2);
            float gv = q2 ? (q1 ? vq : g1) : (q1 ? g2 : g3);
            fv += xv.x * wA0[0] + xv.y * wB0[0] + bb0[0];
            iv += xv.x * wA0[1] + xv.y * wB0[1] + bb0[1];
            ov += xv.x * wA0[2] + xv.y * wB0[2] + bb0[2];
            gv += xv.x * wA0[3] + xv.y * wB0[3] + bb0[3];
            c1a = sigm(fv) * cst0 + sigm(iv) * tanh_fast(gv);
            h1a = sigm(ov) * tanh_fast(c1a);
            cst0 = c1a;
        }
        // ---- tile 1 ----
        float h1b, c1b;
        {
            float v0 = acc1[0], v1 = acc1[1], v2 = acc1[2], v3 = acc1[3];
            float vq = q2 ? (q1 ? v3 : v2) : (q1 ? v1 : v0);
            float s1 = q2 ? (q1 ? v2 : v3) : (q1 ? v0 : v1);
            float s2 = q2 ? (q1 ? v1 : v0) : (q1 ? v3 : v2);
            float s3 = q2 ? (q1 ? v0 : v1) : (q1 ? v2 : v3);
            float g1 = __shfl_xor(s1, 1);
            float g2 = __shfl_xor(s2, 2);
            float g3 = __shfl_xor(s3, 3);
            float fv = q2 ? (q1 ? g3 : g2) : (q1 ? g1 : vq);
            float iv = q2 ? (q1 ? g2 : g3) : (q1 ? vq : g1);
            float ov = q2 ? (q1 ? g1 : vq) : (q1 ? g3 : g2);
            float gv = q2 ? (q1 ? vq : g1) : (q1 ? g2 : g3);
            fv += xv.x * wA1[0] + xv.y * wB1[0] + bb1[0];
            iv += xv.x * wA1[1] + xv.y * wB1[1] + bb1[1];
            ov += xv.x * wA1[2] + xv.y * wB1[2] + bb1[2];
            gv += xv.x * wA1[3] + xv.y * wB1[3] + bb1[3];
            c1b = sigm(fv) * cst1 + sigm(iv) * tanh_fast(gv);
            h1b = sigm(ov) * tanh_fast(c1b);
            cst1 = c1b;
        }

        // ---- pack h,c across cc via shuffles ----
        float ha1 = __shfl_xor(h1a, 4), ha2 = __shfl_xor(h1a, 8), ha3 = __shfl_xor(ha1, 8);
        float hb1 = __shfl_xor(h1b, 4), hb2 = __shfl_xor(h1b, 8), hb3 = __shfl_xor(hb1, 8);
        float ca1 = __shfl_xor(c1a, 4), ca2 = __shfl_xor(c1a, 8), ca3 = __shfl_xor(ca1, 8);
        float cb1 = __shfl_xor(c1b, 4), cb2 = __shfl_xor(c1b, 8), cb3 = __shfl_xor(cb1, 8);

        const unsigned tag  = (unsigned)(t + 1);
        const unsigned tag4 = tag & 15u;
        const int phase = (t + 1) & 1;
        const unsigned long long tpat =
              ((unsigned long long)(tag4 & 1u)        << 14)
            | ((unsigned long long)((tag4 >> 1) & 1u) << 30)
            | ((unsigned long long)((tag4 >> 2) & 1u) << 46)
            | ((unsigned long long)((tag4 >> 3) & 1u) << 62);

        if (t + 1 < TT) {
            // ---- producer: tagged u64 pair, fire-and-forget (no ack) ----
            if (storer) {
                unsigned long long w0 =
                      (unsigned long long)bf16rne(h1a)
                    | ((unsigned long long)bf16rne(ha1) << 16)
                    | ((unsigned long long)bf16rne(ha2) << 32)
                    | ((unsigned long long)bf16rne(ha3) << 48) | tpat;
                unsigned long long w1 =
                      (unsigned long long)bf16rne(h1b)
                    | ((unsigned long long)bf16rne(hb1) << 16)
                    | ((unsigned long long)bf16rne(hb2) << 32)
                    | ((unsigned long long)bf16rne(hb3) << 48) | tpat;
                unsigned long long* dst = slab
                    + ((size_t)(phase * 128 + bSel)) * 128 + slot * 16 + wv * 2;
                __hip_atomic_store(dst,     w0, __ATOMIC_RELAXED, __HIP_MEMORY_SCOPE_AGENT);
                __hip_atomic_store(dst + 1, w1, __ATOMIC_RELAXED, __HIP_MEMORY_SCOPE_AGENT);
            }

            // raw barrier (NO vmcnt drain): all waves have ISSUED their stores
            asm volatile("s_waitcnt lgkmcnt(0)\n\ts_barrier" ::: "memory");

            // flag = hint only (tags are the guarantee); fire-and-forget
            if (tid == 0)
                __hip_atomic_store(&flags[(g * SLOTS + slot) * 16], tag,
                                   __ATOMIC_RELAXED, __HIP_MEMORY_SCOPE_AGENT);

            xv = *(const float2*)(xp + 2 * (t + 1));   // prefetch x(t+1)

            // ---- flag poll (all waves; 8 lines) ----
            {
                long gd = 0;
                for (;;) {
                    unsigned fl = (lane < SLOTS)
                        ? __hip_atomic_load(&flags[(g * SLOTS + lane) * 16],
                                            __ATOMIC_RELAXED, __HIP_MEMORY_SCOPE_AGENT)
                        : tag;
                    if (__all(fl >= tag)) break;
                    __builtin_amdgcn_s_sleep(1);
                    if (++gd > 20000000L) break;   // anti-hang escape
                }
            }

            // ---- bulk refill: 1 u64/thread, tag-validated, rare retry ----
            const unsigned long long* myp = slab
                + ((size_t)(phase * 128 + g * SPG + crow)) * 128 + ck;
            unsigned long long d = __hip_atomic_load(myp, __ATOMIC_RELAXED,
                                                     __HIP_MEMORY_SCOPE_AGENT);
            long gd = 0;
            while ((d & TAGM) != tpat) {
                __builtin_amdgcn_s_sleep(1);
                d = __hip_atomic_load(myp, __ATOMIC_RELAXED,
                                      __HIP_MEMORY_SCOPE_AGENT);
                if (++gd > 3000000L) break;   // anti-hang escape
            }

            // ---- out flush AFTER refill: acks overlap next-step compute ----
            if (storer) {
                size_t oidx = ((size_t)bSel * TT + t) * HH + slot * HCBLK + wv * 8;
                float4 hq0 = {h1a, ha1, ha2, ha3};
                float4 cq0 = {c1a, ca1, ca2, ca3};
                float4 hq1 = {h1b, hb1, hb2, hb3};
                float4 cq1 = {c1b, cb1, cb2, cb3};
                *(float4*)(out + oidx) = hq0;
                *(float4*)(out + oidx + 4) = hq1;
                *(float4*)(out + OSZ + oidx) = cq0;
                *(float4*)(out + OSZ + oidx + 4) = cq1;
            }

            // ---- LDS write + raw barrier (lgkmcnt only) ----
            ldsA[phase][crow][ck ^ (2 * crow)] = d & ~TAGM;
            asm volatile("s_waitcnt lgkmcnt(0)\n\ts_barrier" ::: "memory");
        } else {
            if (storer) {
                size_t oidx = ((size_t)bSel * TT + t) * HH + slot * HCBLK + wv * 8;
                float4 hq0 = {h1a, ha1, ha2, ha3};
                float4 cq0 = {c1a, ca1, ca2, ca3};
                float4 hq1 = {h1b, hb1, hb2, hb3};
                float4 cq1 = {c1b, cb1, cb2, cb3};
                *(float4*)(out + oidx) = hq0;
                *(float4*)(out + oidx + 4) = hq1;
                *(float4*)(out + OSZ + oidx) = cq0;
                *(float4*)(out + OSZ + oidx + 4) = cq1;
            }
        }
    }
}

extern "C" void kernel_launch(void* const* d_in, const int* in_sizes, int n_in,
                              void* d_out, int out_size, void* d_ws, size_t ws_size,
                              hipStream_t stream) {
    const float* x    = (const float*)d_in[0];
    const float* wih  = (const float*)d_in[1];
    const float* whh  = (const float*)d_in[2];
    const float* bias = (const float*)d_in[3];
    float* out = (float*)d_out;
    float* ws  = (float*)d_ws;

    // zero tagged slab (256K) + flag lines (16K) every launch (replay safe)
    hipMemsetAsync(d_ws, 0, 272 * 1024, stream);

    dim3 grid(NG * SLOTS), block(512);
    hipLaunchKernelGGL(lstm_fb, grid, block, 0, stream, x, wih, whh, bias, out, ws);
}

// Round 15
// 3274.551 us; speedup vs baseline: 3.2516x; 1.0349x over previous
//
#include <hip/hip_runtime.h>

#define TT 1000
#define HH 512
#define G4 2048
#define NG 32         // groups
#define SLOTS 8       // blocks per group
#define SPG 4         // seqs per group
#define HCBLK 64      // h-cols per block

typedef __attribute__((ext_vector_type(8))) short bf16x8;
typedef __attribute__((ext_vector_type(4))) float f32x4;

__device__ __forceinline__ float sigm(float v) { return 1.0f / (1.0f + __expf(-v)); }
__device__ __forceinline__ float tanh_fast(float v) { return 2.0f / (1.0f + __expf(-2.0f * v)) - 1.0f; }

__device__ __forceinline__ unsigned short bf16rne(float f) {
    unsigned u = __float_as_uint(f);
    return (unsigned short)((u + 0x7fffu + ((u >> 16) & 1u)) >> 16);
}

// 256 blocks x 512 thr (8 waves, 1/CU). group g = bid&31 owns seqs [g*4,+4);
// slot = bid>>5 owns h-cols [slot*64,+64). W_hh in VGPRs (2 tiles/wave).
// Protocol = R11's proven flag-guarantee exchange:
//   slab store -> vmcnt(0) ack -> barrier -> flag store (flag == guarantee)
//   -> SINGLE-WAVE poll (8 loads in flight, not 64) -> raw-barrier release
//   -> bulk read 1 u64/thread (no validation needed) -> LDS -> raw barrier.
// LDS: [buf][4][132] u64, ^(2*row) swizzle = ZERO bank conflicts (R12-R14).
// Barriers are raw s_barrier (+lgkmcnt only where LDS order matters); the one
// vmcnt(0) is the ack, which also drains out-stores issued a full step ago.
__global__ __launch_bounds__(512, 1)
void lstm_bo(const float* __restrict__ x,     // [B][T][2]
             const float* __restrict__ wih,   // [2][4H]
             const float* __restrict__ whh,   // [H][4H]
             const float* __restrict__ bias,  // [4H]
             float* __restrict__ out,         // h [B][T][H] then c [B][T][H]
             float* ws)
{
    __shared__ unsigned long long ldsA[2][4][132];

    const int bid  = blockIdx.x;
    const int g    = bid & (NG - 1);
    const int slot = bid >> 5;
    const int tid  = threadIdx.x;
    const int wv   = tid >> 6;             // 0..7
    const int lane = tid & 63;
    const int col  = lane & 15;
    const int kb   = lane >> 4;            // 0..3 (k-subchunk)
    const int q    = col & 3;              // gate id 0=f,1=i,2=o,3=g
    const int q1   = q & 1, q2 = q >> 1;
    const int cc   = col >> 2;             // within-tile h-col 0..3
    const int hc0  = slot * HCBLK + wv * 8 + cc;
    const int hc1  = hc0 + 4;

    unsigned long long* slab = (unsigned long long*)ws;          // u64[2][128][128]
    unsigned* flags = (unsigned*)((char*)ws + 256 * 1024);       // [32][8] x 64B

    // zero both LDS buffers (buf0 = h(0) = 0)
    for (int i = tid; i < 2 * 4 * 132; i += 512)
        ((unsigned long long*)ldsA)[i] = 0ULL;

    // ---- one-time: W_hh fragments into registers (2 tiles x 64 VGPR) ----
    const int gc0 = q * 512 + hc0;
    const int gc1 = q * 512 + hc1;
    bf16x8 breg0[16], breg1[16];
    #pragma unroll
    for (int kt = 0; kt < 16; ++kt) {
        bf16x8 f0, f1;
        #pragma unroll
        for (int j = 0; j < 8; ++j) {
            int k = kt * 32 + kb * 8 + j;
            f0[j] = (short)bf16rne(whh[(size_t)k * G4 + gc0]);
            f1[j] = (short)bf16rne(whh[(size_t)k * G4 + gc1]);
        }
        breg0[kt] = f0;
        breg1[kt] = f1;
    }

    float wA0[4], wB0[4], bb0[4], wA1[4], wB1[4], bb1[4];
    #pragma unroll
    for (int j = 0; j < 4; ++j) {
        int a0 = j * 512 + hc0, a1 = j * 512 + hc1;
        wA0[j] = wih[a0]; wB0[j] = wih[G4 + a0]; bb0[j] = bias[a0];
        wA1[j] = wih[a1]; wB1[j] = wih[G4 + a1]; bb1[j] = bias[a1];
    }

    float cst0 = 0.0f, cst1 = 0.0f;
    const size_t OSZ = (size_t)128 * TT * HH;
    const int bSel = g * SPG + q;          // batch index for this lane's row
    const float* xp = x + (size_t)bSel * TT * 2;
    float2 xv = *(const float2*)(xp);      // x(0) prefetched
    const bool storer = (kb == 0) && (cc == 0);

    // this thread's refill word: row crow, u64 ck within the row
    const int crow = tid >> 7;             // 0..3
    const int ck   = tid & 127;            // 0..127

    __syncthreads();

    for (int t = 0; t < TT; ++t) {
        const int rb = t & 1;              // read buffer (h(t))

        // ---- gates = h @ W_hh (K=512; A rows 4..15 zero via exec mask) ----
        f32x4 acc0 = {0.f, 0.f, 0.f, 0.f};
        f32x4 acc1 = {0.f, 0.f, 0.f, 0.f};
        #pragma unroll
        for (int kt = 0; kt < 16; ++kt) {
            bf16x8 a = {0, 0, 0, 0, 0, 0, 0, 0};
            if (col < 4)
                a = *(const bf16x8*)&ldsA[rb][col][(kt * 8 + kb * 2) ^ (2 * col)];
            acc0 = __builtin_amdgcn_mfma_f32_16x16x32_bf16(a, breg0[kt], acc0, 0, 0, 0);
            acc1 = __builtin_amdgcn_mfma_f32_16x16x32_bf16(a, breg1[kt], acc1, 0, 0, 0);
        }

        // ---- tile 0: quad butterfly + gate math ----
        float h1a, c1a;
        {
            float v0 = acc0[0], v1 = acc0[1], v2 = acc0[2], v3 = acc0[3];
            float vq = q2 ? (q1 ? v3 : v2) : (q1 ? v1 : v0);
            float s1 = q2 ? (q1 ? v2 : v3) : (q1 ? v0 : v1);
            float s2 = q2 ? (q1 ? v1 : v0) : (q1 ? v3 : v2);
            float s3 = q2 ? (q1 ? v0 : v1) : (q1 ? v2 : v3);
            float g1 = __shfl_xor(s1, 1);
            float g2 = __shfl_xor(s2, 2);
            float g3 = __shfl_xor(s3, 3);
            float fv = q2 ? (q1 ? g3 : g2) : (q1 ? g1 : vq);
            float iv = q2 ? (q1 ? g2 : g3) : (q1 ? vq : g1);
            float ov = q2 ? (q1 ? g1 : vq) : (q1 ? g3 : g2);
            float gv = q2 ? (q1 ? vq : g1) : (q1 ? g2 : g3);
            fv += xv.x * wA0[0] + xv.y * wB0[0] + bb0[0];
            iv += xv.x * wA0[1] + xv.y * wB0[1] + bb0[1];
            ov += xv.x * wA0[2] + xv.y * wB0[2] + bb0[2];
            gv += xv.x * wA0[3] + xv.y * wB0[3] + bb0[3];
            c1a = sigm(fv) * cst0 + sigm(iv) * tanh_fast(gv);
            h1a = sigm(ov) * tanh_fast(c1a);
            cst0 = c1a;
        }
        // ---- tile 1 ----
        float h1b, c1b;
        {
            float v0 = acc1[0], v1 = acc1[1], v2 = acc1[2], v3 = acc1[3];
            float vq = q2 ? (q1 ? v3 : v2) : (q1 ? v1 : v0);
            float s1 = q2 ? (q1 ? v2 : v3) : (q1 ? v0 : v1);
            float s2 = q2 ? (q1 ? v1 : v0) : (q1 ? v3 : v2);
            float s3 = q2 ? (q1 ? v0 : v1) : (q1 ? v2 : v3);
            float g1 = __shfl_xor(s1, 1);
            float g2 = __shfl_xor(s2, 2);
            float g3 = __shfl_xor(s3, 3);
            float fv = q2 ? (q1 ? g3 : g2) : (q1 ? g1 : vq);
            float iv = q2 ? (q1 ? g2 : g3) : (q1 ? vq : g1);
            float ov = q2 ? (q1 ? g1 : vq) : (q1 ? g3 : g2);
            float gv = q2 ? (q1 ? vq : g1) : (q1 ? g2 : g3);
            fv += xv.x * wA1[0] + xv.y * wB1[0] + bb1[0];
            iv += xv.x * wA1[1] + xv.y * wB1[1] + bb1[1];
            ov += xv.x * wA1[2] + xv.y * wB1[2] + bb1[2];
            gv += xv.x * wA1[3] + xv.y * wB1[3] + bb1[3];
            c1b = sigm(fv) * cst1 + sigm(iv) * tanh_fast(gv);
            h1b = sigm(ov) * tanh_fast(c1b);
            cst1 = c1b;
        }

        // ---- pack h,c across cc via shuffles ----
        float ha1 = __shfl_xor(h1a, 4), ha2 = __shfl_xor(h1a, 8), ha3 = __shfl_xor(ha1, 8);
        float hb1 = __shfl_xor(h1b, 4), hb2 = __shfl_xor(h1b, 8), hb3 = __shfl_xor(hb1, 8);
        float ca1 = __shfl_xor(c1a, 4), ca2 = __shfl_xor(c1a, 8), ca3 = __shfl_xor(ca1, 8);
        float cb1 = __shfl_xor(c1b, 4), cb2 = __shfl_xor(c1b, 8), cb3 = __shfl_xor(cb1, 8);

        const unsigned tag = (unsigned)(t + 1);
        const int phase = (t + 1) & 1;

        if (t + 1 < TT) {
            // ---- producer: u64 pair into group slab ----
            if (storer) {
                unsigned long long w0 =
                      (unsigned long long)bf16rne(h1a)
                    | ((unsigned long long)bf16rne(ha1) << 16)
                    | ((unsigned long long)bf16rne(ha2) << 32)
                    | ((unsigned long long)bf16rne(ha3) << 48);
                unsigned long long w1 =
                      (unsigned long long)bf16rne(h1b)
                    | ((unsigned long long)bf16rne(hb1) << 16)
                    | ((unsigned long long)bf16rne(hb2) << 32)
                    | ((unsigned long long)bf16rne(hb3) << 48);
                unsigned long long* dst = slab
                    + ((size_t)(phase * 128 + bSel)) * 128 + slot * 16 + wv * 2;
                __hip_atomic_store(dst,     w0, __ATOMIC_RELAXED, __HIP_MEMORY_SCOPE_AGENT);
                __hip_atomic_store(dst + 1, w1, __ATOMIC_RELAXED, __HIP_MEMORY_SCOPE_AGENT);
            }

            // ack: slab stores globally visible before anyone raises the flag
            asm volatile("s_waitcnt vmcnt(0)" ::: "memory");
            asm volatile("s_barrier" ::: "memory");

            // flag = GUARANTEE that this block's slab piece is visible
            if (tid == 0)
                __hip_atomic_store(&flags[(g * SLOTS + slot) * 16], tag,
                                   __ATOMIC_RELAXED, __HIP_MEMORY_SCOPE_AGENT);

            // out flush: fire-and-forget; drained by NEXT step's ack (a full
            // poll+refill+compute later)
            if (storer) {
                size_t oidx = ((size_t)bSel * TT + t) * HH + slot * HCBLK + wv * 8;
                float4 hq0 = {h1a, ha1, ha2, ha3};
                float4 cq0 = {c1a, ca1, ca2, ca3};
                float4 hq1 = {h1b, hb1, hb2, hb3};
                float4 cq1 = {c1b, cb1, cb2, cb3};
                *(float4*)(out + oidx) = hq0;
                *(float4*)(out + oidx + 4) = hq1;
                *(float4*)(out + OSZ + oidx) = cq0;
                *(float4*)(out + OSZ + oidx + 4) = cq1;
            }

            xv = *(const float2*)(xp + 2 * (t + 1));   // prefetch x(t+1)

            // ---- SINGLE-WAVE flag poll (8 loads/iter/block, not 64) ----
            if (wv == 0) {
                long gd = 0;
                for (;;) {
                    unsigned fl = (lane < SLOTS)
                        ? __hip_atomic_load(&flags[(g * SLOTS + lane) * 16],
                                            __ATOMIC_RELAXED, __HIP_MEMORY_SCOPE_AGENT)
                        : tag;
                    if (__all(fl >= tag)) break;
                    __builtin_amdgcn_s_sleep(1);
                    if (++gd > 20000000L) break;   // anti-hang escape
                }
            }
            // release: waves 1-7 were parked here issuing nothing
            asm volatile("s_barrier" ::: "memory");

            // ---- bulk refill: 1 u64/thread, guaranteed fresh ----
            const unsigned long long* myp = slab
                + ((size_t)(phase * 128 + g * SPG + crow)) * 128 + ck;
            unsigned long long d = __hip_atomic_load(myp, __ATOMIC_RELAXED,
                                                     __HIP_MEMORY_SCOPE_AGENT);
            ldsA[phase][crow][ck ^ (2 * crow)] = d;

            asm volatile("s_waitcnt lgkmcnt(0)\n\ts_barrier" ::: "memory");
        } else {
            if (storer) {
                size_t oidx = ((size_t)bSel * TT + t) * HH + slot * HCBLK + wv * 8;
                float4 hq0 = {h1a, ha1, ha2, ha3};
                float4 cq0 = {c1a, ca1, ca2, ca3};
                float4 hq1 = {h1b, hb1, hb2, hb3};
                float4 cq1 = {c1b, cb1, cb2, cb3};
                *(float4*)(out + oidx) = hq0;
                *(float4*)(out + oidx + 4) = hq1;
                *(float4*)(out + OSZ + oidx) = cq0;
                *(float4*)(out + OSZ + oidx + 4) = cq1;
            }
        }
    }
}

extern "C" void kernel_launch(void* const* d_in, const int* in_sizes, int n_in,
                              void* d_out, int out_size, void* d_ws, size_t ws_size,
                              hipStream_t stream) {
    const float* x    = (const float*)d_in[0];
    const float* wih  = (const float*)d_in[1];
    const float* whh  = (const float*)d_in[2];
    const float* bias = (const float*)d_in[3];
    float* out = (float*)d_out;
    float* ws  = (float*)d_ws;

    // zero the flag lines every launch (slab needs no reset: flag-guarded)
    hipMemsetAsync((char*)d_ws + 256 * 1024, 0, NG * SLOTS * 16 * sizeof(unsigned), stream);

    dim3 grid(NG * SLOTS), block(512);
    hipLaunchKernelGGL(lstm_bo, grid, block, 0, stream, x, wih, whh, bias, out, ws);
}